// Round 12
// baseline (3442.078 us; speedup 1.0000x reference)
//
#include <hip/hip_runtime.h>

#define DD 1536
#define TT 512
#define BB 64
#define BD (BB*DD)      /* 98304 */
#define TBD (TT*BD)     /* 50331648 */
#define NWG 96          /* 24 feature-groups x 4 batch-quadrants */

typedef __attribute__((ext_vector_type(8))) short short8;
typedef __attribute__((ext_vector_type(4))) float f32x4;

__device__ __forceinline__ short f2bf(float f) {
  unsigned u = __builtin_bit_cast(unsigned, f);
  u += 0x7FFFu + ((u >> 16) & 1u);   // RNE
  return (short)(u >> 16);
}

// coherent (device-scope, L1/L2-bypassing) 4B store -> Infinity Cache
__device__ __forceinline__ void st_coh_b32(int* p, int v) {
  asm volatile("global_store_dword %0, %1, off sc0 sc1" :: "v"(p), "v"(v) : "memory");
}

// coherent 16B load from Infinity Cache (bypasses L1/L2)
#define LDQ(dst, addr, imm) \
  asm volatile("global_load_dwordx4 %0, %1, off offset:" #imm " sc0 sc1" \
               : "=v"(dst) : "v"(addr) : "memory")

// ---------------- power iteration helpers (f32 exact) ----------------

__global__ __launch_bounds__(256) void k_matvec_row(
    const float* __restrict__ W, const float* __restrict__ x, float* __restrict__ y) {
  int wave = (blockIdx.x * 256 + threadIdx.x) >> 6;
  int lane = threadIdx.x & 63;
  const float* Wr = W + (size_t)wave * DD;
  float acc = 0.f;
  for (int j = lane; j < DD; j += 64) acc += Wr[j] * x[j];
  for (int off = 32; off; off >>= 1) acc += __shfl_down(acc, off, 64);
  if (lane == 0) y[wave] = acc;
}

__global__ __launch_bounds__(256) void k_matvec_colf(
    const float* __restrict__ W, const float* __restrict__ x, float* __restrict__ y) {
  int j = blockIdx.x * 256 + threadIdx.x;
  float a0 = 0.f, a1 = 0.f, a2 = 0.f, a3 = 0.f;
  for (int i = 0; i < DD; i += 4) {
    a0 += W[(size_t)(i + 0) * DD + j] * x[i + 0];
    a1 += W[(size_t)(i + 1) * DD + j] * x[i + 1];
    a2 += W[(size_t)(i + 2) * DD + j] * x[i + 2];
    a3 += W[(size_t)(i + 3) * DD + j] * x[i + 3];
  }
  y[j] = (a0 + a1) + (a2 + a3);
}

__global__ __launch_bounds__(256) void k_scale(
    const float* __restrict__ t5, const float* __restrict__ t6,
    const float* __restrict__ log_radius, float* __restrict__ s_out) {
  __shared__ float red[8];
  int tid = threadIdx.x;
  float a5 = 0.f, a6 = 0.f;
  for (int i = tid; i < DD; i += 256) { float v5 = t5[i], v6 = t6[i]; a5 += v5*v5; a6 += v6*v6; }
  for (int off = 32; off; off >>= 1) { a5 += __shfl_down(a5, off, 64); a6 += __shfl_down(a6, off, 64); }
  int w = tid >> 6, lane = tid & 63;
  if (lane == 0) { red[w] = a5; red[4 + w] = a6; }
  __syncthreads();
  if (tid == 0) {
    float s5 = red[0] + red[1] + red[2] + red[3];
    float s6 = red[4] + red[5] + red[6] + red[7];
    float sigma = sqrtf(s6 / s5);
    float lr = log_radius[0];
    float target = 0.999f / (1.f + expf(-lr));
    s_out[0] = target / (sigma + 1e-8f);
  }
}

// ---------------- bf16 pre-conversion of x (gated on ws_size) ----------------
__global__ __launch_bounds__(256) void k_conv(
    const float* __restrict__ in, short* __restrict__ out, int n8) {
  int i = blockIdx.x * 256 + threadIdx.x;
  int stride = gridDim.x * 256;
  for (; i < n8; i += stride) {
    const float4* p = (const float4*)(in + (size_t)i * 8);
    float4 a = p[0], b = p[1];
    short8 v;
    v[0]=f2bf(a.x); v[1]=f2bf(a.y); v[2]=f2bf(a.z); v[3]=f2bf(a.w);
    v[4]=f2bf(b.x); v[5]=f2bf(b.y); v[6]=f2bf(b.z); v[7]=f2bf(b.w);
    *(short8*)(out + (size_t)i * 8) = v;
  }
}

// ---------------- fused recurrence + A-GEMM ----------------
// R11 exchange protocol unchanged (per-wave sub-flags, 3-buffer rotation,
// coherent packed h stores, swizzled b32 reduce). NEW: A[t+1] = x[t+1]@Wx^T + b
// computed per-WG during step t's slack (24 MFMAs vs register-resident Wx tile,
// reduce via a third LDS buffer) -> no standalone GEMM, no A store/reload.
template<bool BIG>
__global__ __launch_bounds__(512, 2) void k_recur(
    const float* __restrict__ Wh, const float* __restrict__ Wx,
    const float* __restrict__ h0, const float* __restrict__ x,
    const short* __restrict__ xb, const float* __restrict__ z,
    const float* __restrict__ sp, const float* __restrict__ bias,
    float* __restrict__ outs, float* __restrict__ hall,
    short* __restrict__ hbuf, int* __restrict__ flags) {
  __shared__ f32x4 REDS[2][2048];  // 2 x 32 KB (h reduce, double-buffered)
  __shared__ f32x4 ARED[2048];     // 32 KB (A reduce, single-buffered)
  const int tid = threadIdx.x;
  const int lane = tid & 63;
  const int wv = tid >> 6;         // 0..7
  const int wgid = blockIdx.x;     // 0..95
  const int fg = wgid >> 2;        // 0..23
  const int mq = wgid & 3;
  const int n0 = fg * 64;
  const int m0 = mq * 16;

  const int nl = lane & 15;
  const int hi8 = (lane >> 4) << 3;
  const int kw = wv * 192;         // wave's K-slice base

  // ---- one-time: Wh and Wx tiles -> registers (f32 -> bf16) ----
  short8 bfr[6][4], wxr[6][4];
#pragma unroll
  for (int j = 0; j < 6; ++j)
#pragma unroll
    for (int f = 0; f < 4; ++f) {
      const float* gp = Wh + (size_t)(n0 + f * 16 + nl) * DD + kw + j * 32 + hi8;
      float4 a0 = *(const float4*)gp;
      float4 a1 = *(const float4*)(gp + 4);
      short8 v;
      v[0]=f2bf(a0.x); v[1]=f2bf(a0.y); v[2]=f2bf(a0.z); v[3]=f2bf(a0.w);
      v[4]=f2bf(a1.x); v[5]=f2bf(a1.y); v[6]=f2bf(a1.z); v[7]=f2bf(a1.w);
      bfr[j][f] = v;
      const float* gq = Wx + (size_t)(n0 + f * 16 + nl) * DD + kw + j * 32 + hi8;
      float4 b0 = *(const float4*)gq;
      float4 b1 = *(const float4*)(gq + 4);
      short8 w_;
      w_[0]=f2bf(b0.x); w_[1]=f2bf(b0.y); w_[2]=f2bf(b0.z); w_[3]=f2bf(b0.w);
      w_[4]=f2bf(b1.x); w_[5]=f2bf(b1.y); w_[6]=f2bf(b1.z); w_[7]=f2bf(b1.w);
      wxr[j][f] = w_;
    }

  // epilogue geometry: r = wv + 8*half keeps ri wave-uniform; c,c+1 per thread
  const int r = wv + ((lane >> 5) << 3);   // 0..15
  const int c = (lane & 31) * 2;           // 0..62 even
  const int f0 = c >> 4;
  const int c15 = c & 15;
  const int l2a = ((r >> 2) << 4) | c15;
  const int l2b = l2a + 1;
  const int ri = r & 3;
  const size_t eidx = (size_t)(m0 + r) * DD + n0 + c;        // element in [B,D]
  const size_t sliceoff = (size_t)(m0 + nl) * DD + kw + hi8; // h/x slice base (elements)

  int* myflag = flags + ((mq * 24 + fg) * 8 + wv) * 16;     // own 64B line
  const int* cflag = flags + (((mq * 24 + wv * 3 + (lane >> 3)) * 8) + (lane & 7)) * 16;

  // reduce swizzle constants
  const int lsw = lane ^ ((lane >> 5) & 1);
  const int ia = (f0 * 64 + (l2a ^ ((l2a >> 5) & 1))) * 4 + ((ri + f0) & 3);
  const int ib = (f0 * 64 + (l2b ^ ((l2b >> 5) & 1))) * 4 + ((ri + f0) & 3);

  // 3 rotating h buffers
  short* pg = hbuf;                // read  h[t]
  short* pn = hbuf + BD;           // write h[t+1]
  short* pq = hbuf + 2 * BD;       // spare

  const float bv0 = bias[n0 + c], bv1 = bias[n0 + c + 1];
  const float sv = sp[0];

  // A[tt] tile compute: x[tt] slice (bf16 or f32+convert) x Wx regs -> pa, pay
  auto computeA = [&](int tt, float& oA0, float& oA1) {
    const size_t xo = (size_t)tt * BD + sliceoff;
    short8 xa[6];
    if constexpr (BIG) {
#pragma unroll
      for (int ci = 0; ci < 6; ++ci)
        xa[ci] = *(const short8*)(xb + xo + ci * 32);
    } else {
#pragma unroll
      for (int ci = 0; ci < 6; ++ci) {
        const float* gp = x + xo + ci * 32;
        float4 q0 = *(const float4*)gp, q1 = *(const float4*)(gp + 4);
        short8 v;
        v[0]=f2bf(q0.x); v[1]=f2bf(q0.y); v[2]=f2bf(q0.z); v[3]=f2bf(q0.w);
        v[4]=f2bf(q1.x); v[5]=f2bf(q1.y); v[6]=f2bf(q1.z); v[7]=f2bf(q1.w);
        xa[ci] = v;
      }
    }
    f32x4 b0 = (f32x4){0,0,0,0}, b1 = (f32x4){0,0,0,0};
    f32x4 b2 = (f32x4){0,0,0,0}, b3 = (f32x4){0,0,0,0};
#pragma unroll
    for (int j = 0; j < 6; ++j) {
      b0 = __builtin_amdgcn_mfma_f32_16x16x32_bf16(xa[j], wxr[j][0], b0, 0, 0, 0);
      b1 = __builtin_amdgcn_mfma_f32_16x16x32_bf16(xa[j], wxr[j][1], b1, 0, 0, 0);
      b2 = __builtin_amdgcn_mfma_f32_16x16x32_bf16(xa[j], wxr[j][2], b2, 0, 0, 0);
      b3 = __builtin_amdgcn_mfma_f32_16x16x32_bf16(xa[j], wxr[j][3], b3, 0, 0, 0);
    }
#define WRA(f, accv) { f32x4 t_; \
    t_[(0 + f) & 3] = accv[0]; t_[(1 + f) & 3] = accv[1]; \
    t_[(2 + f) & 3] = accv[2]; t_[(3 + f) & 3] = accv[3]; \
    ARED[wv * 256 + f * 64 + lsw] = t_; }
    WRA(0, b0) WRA(1, b1) WRA(2, b2) WRA(3, b3)
#undef WRA
    __syncthreads();
    const float* Af = (const float*)ARED;
    float s0 = 0.f, s1 = 0.f;
#pragma unroll
    for (int w2 = 0; w2 < 8; ++w2) {
      s0 += Af[w2 * 1024 + ia];
      s1 += Af[w2 * 1024 + ib];
    }
    oA0 = s0 + bv0; oA1 = s1 + bv1;
  };

  // init: hall[0] = h0 (f32); buf0 = bf16(h0) coherent packed; per-wave flag gen 1
  {
    float vx = h0[eidx], vy = h0[eidx + 1];
    hall[eidx] = vx; hall[eidx + 1] = vy;
    unsigned pk = (unsigned)(unsigned short)f2bf(vx)
                | ((unsigned)(unsigned short)f2bf(vy) << 16);
    st_coh_b32((int*)(pg + eidx), (int)pk);
  }
  asm volatile("s_waitcnt vmcnt(0)" ::: "memory");
  if (lane == 0) st_coh_b32(myflag, 1);

  // prologue: A[0] + z[0]
  float pa, pay;
  computeA(0, pa, pay);
  float pz = z[eidx], pzy = z[eidx + 1];

  for (int t = 0; t < TT; ++t) {
    const bool last = (t == TT - 1);

    // wait the 24 producer sub-flags (3 WGs x 8 waves); monotonic, bounded
    if (lane < 24) {
      int it = 0;
      for (;;) {
        int v = __hip_atomic_load(cflag, __ATOMIC_RELAXED, __HIP_MEMORY_SCOPE_AGENT);
        if (v >= t + 1 || ++it > (1 << 20)) break;
        __builtin_amdgcn_s_sleep(1);
      }
    }

    // 6 coherent 16B A-loads (wave's 192-k slice of rows m0..m0+15)
    const short* hp = pg + sliceoff;
    short8 a0, a1, a2, a3, a4, a5;
    LDQ(a0, hp, 0);
    LDQ(a1, hp, 64);
    LDQ(a2, hp, 128);
    LDQ(a3, hp, 192);
    LDQ(a4, hp, 256);
    LDQ(a5, hp, 320);
    asm volatile("s_waitcnt vmcnt(0)" ::: "memory");
    __builtin_amdgcn_sched_barrier(0);

    f32x4 acc0 = (f32x4){0,0,0,0}, acc1 = (f32x4){0,0,0,0};
    f32x4 acc2 = (f32x4){0,0,0,0}, acc3 = (f32x4){0,0,0,0};
#define MF4(aa, j) \
    acc0 = __builtin_amdgcn_mfma_f32_16x16x32_bf16(aa, bfr[j][0], acc0, 0, 0, 0); \
    acc1 = __builtin_amdgcn_mfma_f32_16x16x32_bf16(aa, bfr[j][1], acc1, 0, 0, 0); \
    acc2 = __builtin_amdgcn_mfma_f32_16x16x32_bf16(aa, bfr[j][2], acc2, 0, 0, 0); \
    acc3 = __builtin_amdgcn_mfma_f32_16x16x32_bf16(aa, bfr[j][3], acc3, 0, 0, 0);
    MF4(a0, 0) MF4(a1, 1) MF4(a2, 2) MF4(a3, 3) MF4(a4, 4) MF4(a5, 5)
#undef MF4

    // cross-wave K reduce: swizzled b32 (R11)
    f32x4* R = REDS[t & 1];
    {
#define WR(f, accv) { f32x4 wv_; \
      wv_[(0 + f) & 3] = accv[0]; wv_[(1 + f) & 3] = accv[1]; \
      wv_[(2 + f) & 3] = accv[2]; wv_[(3 + f) & 3] = accv[3]; \
      R[wv * 256 + f * 64 + lsw] = wv_; }
      WR(0, acc0) WR(1, acc1) WR(2, acc2) WR(3, acc3)
#undef WR
    }
    __syncthreads();
    const float* Rf = (const float*)R;
    float s0 = 0.f, s1 = 0.f;
#pragma unroll
    for (int w2 = 0; w2 < 8; ++w2) {
      s0 += Rf[w2 * 1024 + ia];
      s1 += Rf[w2 * 1024 + ib];
    }

    // critical path: h_new -> coherent packed store -> per-wave ack -> sub-flag
    float h0v = tanhf(pa + sv * s0);
    float h1v = tanhf(pay + sv * s1);
    if (!last) {
      unsigned pk = (unsigned)(unsigned short)f2bf(h0v)
                  | ((unsigned)(unsigned short)f2bf(h1v) << 16);
      st_coh_b32((int*)(pn + eidx), (int)pk);
      asm volatile("s_waitcnt vmcnt(0)" ::: "memory");   // this wave's h-store acked at IF
      if (lane == 0) st_coh_b32(myflag, t + 2);          // single-writer release
    }

    // off-critical-path tail (drains during the next spin)
    size_t tb = (size_t)t * BD;
    hall[tb + BD + eidx] = h0v;
    hall[tb + BD + eidx + 1] = h1v;
    outs[tb + eidx]     = h0v * (pz  / (1.f + __expf(-pz)));
    outs[tb + eidx + 1] = h1v * (pzy / (1.f + __expf(-pzy)));
    if (!last) {
      computeA(t + 1, pa, pay);       // A[t+1] hidden in spin slack
      size_t nb = tb + BD + eidx;
      pz = z[nb]; pzy = z[nb + 1];
    }
    // rotate buffers: h[t+1] becomes the read buffer
    short* tmp = pg; pg = pn; pn = pq; pq = tmp;
  }
}

// ---------------- launcher ----------------
extern "C" void kernel_launch(void* const* d_in, const int* in_sizes, int n_in,
                              void* d_out, int out_size, void* d_ws, size_t ws_size,
                              hipStream_t stream) {
  const float* x  = (const float*)d_in[0];
  const float* z  = (const float*)d_in[1];
  const float* h0 = (const float*)d_in[2];
  const float* Wx = (const float*)d_in[3];
  const float* Wh = (const float*)d_in[4];
  const float* b  = (const float*)d_in[5];
  const float* lr = (const float*)d_in[6];
  const float* u  = (const float*)d_in[7];

  float* outs = (float*)d_out;
  float* hall = outs + (size_t)TBD;

  char* ws = (char*)d_ws;
  float* vA = (float*)ws;
  float* vB = vA + DD;
  float* vC = vB + DD;
  float* vD = vC + DD;
  float* sS = vD + DD;                    // @24576
  int*   flags = (int*)(ws + 32768);      // 96 WGs x 8 waves x 64B = 48 KB
  short* hbuf  = (short*)(ws + 131072);   // 3 x BD bf16 = 576 KB
  short* xb    = (short*)(ws + ((size_t)1 << 20));   // bf16 x (96 MB), gated

  const size_t need = ((size_t)1 << 20) + (size_t)TBD * 2 + 1024;
  const bool big = ws_size >= need;

  // bf16 pre-convert x (if workspace allows)
  if (big)
    hipLaunchKernelGGL(k_conv, dim3(2048), dim3(256), 0, stream, x, xb, TBD / 8);

  // power iteration chain
  hipLaunchKernelGGL(k_matvec_colf, dim3(6),   dim3(256), 0, stream, Wh, u,  vA);
  hipLaunchKernelGGL(k_matvec_row,  dim3(384), dim3(256), 0, stream, Wh, vA, vB);
  hipLaunchKernelGGL(k_matvec_colf, dim3(6),   dim3(256), 0, stream, Wh, vB, vA);
  hipLaunchKernelGGL(k_matvec_row,  dim3(384), dim3(256), 0, stream, Wh, vA, vB);
  hipLaunchKernelGGL(k_matvec_colf, dim3(6),   dim3(256), 0, stream, Wh, vB, vC);
  hipLaunchKernelGGL(k_matvec_row,  dim3(384), dim3(256), 0, stream, Wh, vC, vD);
  hipLaunchKernelGGL(k_scale, dim3(1), dim3(256), 0, stream, vC, vD, lr, sS);

  // zero sub-flag array each launch (graph-capture-safe)
  hipMemsetAsync(flags, 0, 49152, stream);

  // fused cooperative kernel
  void* args[12] = {(void*)&Wh, (void*)&Wx, (void*)&h0, (void*)&x, (void*)&xb,
                    (void*)&z, (void*)&sS, (void*)&b,
                    (void*)&outs, (void*)&hall, (void*)&hbuf, (void*)&flags};
  if (big)
    hipLaunchCooperativeKernel((const void*)k_recur<true>,  dim3(NWG), dim3(512), args, 0, stream);
  else
    hipLaunchCooperativeKernel((const void*)k_recur<false>, dim3(NWG), dim3(512), args, 0, stream);
}

// Round 13
// 2287.299 us; speedup vs baseline: 1.5049x; 1.5049x over previous
//
#include <hip/hip_runtime.h>

#define DD 1536
#define TT 512
#define BB 64
#define BD (BB*DD)      /* 98304 */
#define TBD (TT*BD)     /* 50331648 */
#define NWG 96          /* 24 feature-groups x 4 batch-quadrants */

typedef __attribute__((ext_vector_type(8))) short short8;
typedef __attribute__((ext_vector_type(4))) float f32x4;

__device__ __forceinline__ short f2bf(float f) {
  unsigned u = __builtin_bit_cast(unsigned, f);
  u += 0x7FFFu + ((u >> 16) & 1u);   // RNE
  return (short)(u >> 16);
}

// coherent (device-scope, L1/L2-bypassing) 4B store -> Infinity Cache
__device__ __forceinline__ void st_coh_b32(int* p, int v) {
  asm volatile("global_store_dword %0, %1, off sc0 sc1" :: "v"(p), "v"(v) : "memory");
}

// coherent 16B load from Infinity Cache (bypasses L1/L2)
#define LDQ(dst, addr, imm) \
  asm volatile("global_load_dwordx4 %0, %1, off offset:" #imm " sc0 sc1" \
               : "=v"(dst) : "v"(addr) : "memory")

__device__ __forceinline__ float ld_coh_f(const float* p) {
  return __hip_atomic_load(p, __ATOMIC_RELAXED, __HIP_MEMORY_SCOPE_AGENT);
}

// ---------------- fused power iteration (one cooperative kernel) ----------------
// 6 matvecs + scale with internal flag barriers. Cross-phase data: colf outputs
// via device-scope atomicAdd (coherence point); row outputs via coherent stores;
// all cross-phase reads via relaxed agent atomic loads. Bounded spins.
__global__ __launch_bounds__(256) void k_power(
    const float* __restrict__ Wh, const float* __restrict__ u,
    const float* __restrict__ lr, float* __restrict__ base,
    int* __restrict__ pflags) {
  __shared__ float red[8];
  const int tid = threadIdx.x;
  const int lane = tid & 63;
  const int wgid = blockIdx.x;     // 0..383

  float* vA = base;                // t1 (colf out, pre-zeroed)
  float* vB = base + 1536;         // t2 (row out)
  float* vC = base + 3072;         // t3 (colf out, pre-zeroed)
  float* vD = base + 4608;         // t4 (row out)
  float* vE = base + 6144;         // t5 (colf out, pre-zeroed)
  float* vF = base + 7680;         // t6 (row out)
  float* sS = base + 9216;

  auto bar = [&](int gen) {
    asm volatile("s_waitcnt vmcnt(0)" ::: "memory");
    __syncthreads();
    if (tid == 0) st_coh_b32(pflags + wgid * 16, gen);
    int it = 0;
    for (;;) {
      int v0 = __hip_atomic_load(pflags + tid * 16, __ATOMIC_RELAXED, __HIP_MEMORY_SCOPE_AGENT);
      int v1 = (tid < 128)
        ? __hip_atomic_load(pflags + (256 + tid) * 16, __ATOMIC_RELAXED, __HIP_MEMORY_SCOPE_AGENT)
        : gen;
      if ((v0 >= gen && v1 >= gen) || ++it > (1 << 20)) break;
      __builtin_amdgcn_s_sleep(1);
    }
    __syncthreads();
  };

  // y[j] += partial sum_i W[i,j] src[i]   (WGs 0..95: 6 j-tiles x 16 i-chunks)
  auto colf = [&](const float* src, float* dst) {
    if (wgid < 96) {
      int jt = wgid % 6, ic = wgid / 6;
      int j = jt * 256 + tid;
      int i0 = ic * 96;
      float a0 = 0.f, a1 = 0.f, a2 = 0.f, a3 = 0.f;
      for (int i = i0; i < i0 + 96; i += 4) {
        a0 += Wh[(size_t)(i + 0) * DD + j] * ld_coh_f(src + i + 0);
        a1 += Wh[(size_t)(i + 1) * DD + j] * ld_coh_f(src + i + 1);
        a2 += Wh[(size_t)(i + 2) * DD + j] * ld_coh_f(src + i + 2);
        a3 += Wh[(size_t)(i + 3) * DD + j] * ld_coh_f(src + i + 3);
      }
      atomicAdd(&dst[j], (a0 + a1) + (a2 + a3));
    }
  };

  // y[row] = sum_j W[row,j] src[j]   (1536 waves = 1 row/wave)
  auto rowf = [&](const float* src, float* dst) {
    int row = wgid * 4 + (tid >> 6);
    const float* Wr = Wh + (size_t)row * DD;
    float acc = 0.f;
    for (int j = lane; j < DD; j += 64) acc += Wr[j] * ld_coh_f(src + j);
    for (int off = 32; off; off >>= 1) acc += __shfl_down(acc, off, 64);
    if (lane == 0) st_coh_b32((int*)&dst[row], __builtin_bit_cast(int, acc));
  };

  colf(u,  vA); bar(1);
  rowf(vA, vB); bar(2);
  colf(vB, vC); bar(3);
  rowf(vC, vD); bar(4);
  colf(vD, vE); bar(5);
  rowf(vE, vF); bar(6);

  if (wgid == 0) {
    float a5 = 0.f, a6 = 0.f;
    for (int i = tid; i < DD; i += 256) {
      float v5 = ld_coh_f(vE + i), v6 = ld_coh_f(vF + i);
      a5 += v5 * v5; a6 += v6 * v6;
    }
    for (int off = 32; off; off >>= 1) { a5 += __shfl_down(a5, off, 64); a6 += __shfl_down(a6, off, 64); }
    int w = tid >> 6;
    if (lane == 0) { red[w] = a5; red[4 + w] = a6; }
    __syncthreads();
    if (tid == 0) {
      float s5 = red[0] + red[1] + red[2] + red[3];
      float s6 = red[4] + red[5] + red[6] + red[7];
      float sigma = sqrtf(s6 / s5);
      float lrv = lr[0];
      float target = 0.999f / (1.f + expf(-lrv));
      sS[0] = target / (sigma + 1e-8f);
    }
  }
}

// ---------------- bf16 pre-conversion (gated on ws_size) ----------------
__global__ __launch_bounds__(256) void k_conv(
    const float* __restrict__ in, short* __restrict__ out, int n8) {
  int i = blockIdx.x * 256 + threadIdx.x;
  int stride = gridDim.x * 256;
  for (; i < n8; i += stride) {
    const float4* p = (const float4*)(in + (size_t)i * 8);
    float4 a = p[0], b = p[1];
    short8 v;
    v[0]=f2bf(a.x); v[1]=f2bf(a.y); v[2]=f2bf(a.z); v[3]=f2bf(a.w);
    v[4]=f2bf(b.x); v[5]=f2bf(b.y); v[6]=f2bf(b.z); v[7]=f2bf(b.w);
    *(short8*)(out + (size_t)i * 8) = v;
  }
}

// ---------------- phase 1a: A = x @ Wx^T + b (f32 inputs, fallback) ----------------
__global__ __launch_bounds__(256) void k_gemm_xA(
    const float* __restrict__ x, const float* __restrict__ Wx,
    const float* __restrict__ bias, float* __restrict__ Aout) {
  __shared__ short As[128 * 64];
  __shared__ short Bs[128 * 64];
  const int tid = threadIdx.x;
  const int lane = tid & 63;
  const int w = tid >> 6;
  const int n0 = blockIdx.x * 128;
  const int m0 = blockIdx.y * 128;
  const int mq = (w >> 1) * 64;
  const int nq = (w & 1) * 64;

  f32x4 acc[4][4];
#pragma unroll
  for (int i = 0; i < 4; ++i)
#pragma unroll
    for (int j = 0; j < 4; ++j) acc[i][j] = (f32x4){0.f, 0.f, 0.f, 0.f};

  const int r0 = tid >> 3;
  const int c8 = tid & 7;

  for (int k0 = 0; k0 < DD; k0 += 64) {
    __syncthreads();
#pragma unroll
    for (int c = 0; c < 4; ++c) {
      int row = c * 32 + r0;
      const float4* gx = (const float4*)(x + (size_t)(m0 + row) * DD + k0 + c8 * 8);
      const float4* gw = (const float4*)(Wx + (size_t)(n0 + row) * DD + k0 + c8 * 8);
      float4 x0 = gx[0], x1 = gx[1];
      float4 w0 = gw[0], w1 = gw[1];
      short8 xv, wv;
      xv[0]=f2bf(x0.x); xv[1]=f2bf(x0.y); xv[2]=f2bf(x0.z); xv[3]=f2bf(x0.w);
      xv[4]=f2bf(x1.x); xv[5]=f2bf(x1.y); xv[6]=f2bf(x1.z); xv[7]=f2bf(x1.w);
      wv[0]=f2bf(w0.x); wv[1]=f2bf(w0.y); wv[2]=f2bf(w0.z); wv[3]=f2bf(w0.w);
      wv[4]=f2bf(w1.x); wv[5]=f2bf(w1.y); wv[6]=f2bf(w1.z); wv[7]=f2bf(w1.w);
      int so = (row * 64 + c8 * 8) ^ ((row & 7) << 3);
      *(short8*)&As[so] = xv;
      *(short8*)&Bs[so] = wv;
    }
    __syncthreads();
#pragma unroll
    for (int kk = 0; kk < 64; kk += 32) {
      short8 af[4], bfr[4];
#pragma unroll
      for (int f = 0; f < 4; ++f) {
        int ar = mq + f * 16 + (lane & 15);
        int k = kk + ((lane >> 4) << 3);
        af[f] = *(const short8*)&As[(ar * 64 + k) ^ ((ar & 7) << 3)];
        int br = nq + f * 16 + (lane & 15);
        bfr[f] = *(const short8*)&Bs[(br * 64 + k) ^ ((br & 7) << 3)];
      }
#pragma unroll
      for (int i = 0; i < 4; ++i)
#pragma unroll
        for (int j = 0; j < 4; ++j)
          acc[i][j] = __builtin_amdgcn_mfma_f32_16x16x32_bf16(af[i], bfr[j], acc[i][j], 0, 0, 0);
    }
  }
#pragma unroll
  for (int i = 0; i < 4; ++i) {
    int rbase = m0 + mq + i * 16 + ((lane >> 4) << 2);
#pragma unroll
    for (int j = 0; j < 4; ++j) {
      int col = n0 + nq + j * 16 + (lane & 15);
      float bv = bias[col];
#pragma unroll
      for (int r = 0; r < 4; ++r)
        Aout[(size_t)(rbase + r) * DD + col] = acc[i][j][r] + bv;
    }
  }
}

// ---------------- phase 1b: same GEMM, bf16 pre-converted inputs ----------------
__global__ __launch_bounds__(256) void k_gemm_b(
    const short* __restrict__ xb, const short* __restrict__ Wxb,
    const float* __restrict__ bias, float* __restrict__ Aout) {
  __shared__ short As[128 * 64];
  __shared__ short Bs[128 * 64];
  const int tid = threadIdx.x;
  const int lane = tid & 63;
  const int w = tid >> 6;
  const int n0 = blockIdx.x * 128;
  const int m0 = blockIdx.y * 128;
  const int mq = (w >> 1) * 64;
  const int nq = (w & 1) * 64;

  f32x4 acc[4][4];
#pragma unroll
  for (int i = 0; i < 4; ++i)
#pragma unroll
    for (int j = 0; j < 4; ++j) acc[i][j] = (f32x4){0.f, 0.f, 0.f, 0.f};

  const int r0 = tid >> 3;
  const int c8 = tid & 7;

  for (int k0 = 0; k0 < DD; k0 += 64) {
    __syncthreads();
#pragma unroll
    for (int c = 0; c < 4; ++c) {
      int row = c * 32 + r0;
      short8 xv = *(const short8*)(xb  + (size_t)(m0 + row) * DD + k0 + c8 * 8);
      short8 wv = *(const short8*)(Wxb + (size_t)(n0 + row) * DD + k0 + c8 * 8);
      int so = (row * 64 + c8 * 8) ^ ((row & 7) << 3);
      *(short8*)&As[so] = xv;
      *(short8*)&Bs[so] = wv;
    }
    __syncthreads();
#pragma unroll
    for (int kk = 0; kk < 64; kk += 32) {
      short8 af[4], bfr[4];
#pragma unroll
      for (int f = 0; f < 4; ++f) {
        int ar = mq + f * 16 + (lane & 15);
        int k = kk + ((lane >> 4) << 3);
        af[f] = *(const short8*)&As[(ar * 64 + k) ^ ((ar & 7) << 3)];
        int br = nq + f * 16 + (lane & 15);
        bfr[f] = *(const short8*)&Bs[(br * 64 + k) ^ ((br & 7) << 3)];
      }
#pragma unroll
      for (int i = 0; i < 4; ++i)
#pragma unroll
        for (int j = 0; j < 4; ++j)
          acc[i][j] = __builtin_amdgcn_mfma_f32_16x16x32_bf16(af[i], bfr[j], acc[i][j], 0, 0, 0);
    }
  }
#pragma unroll
  for (int i = 0; i < 4; ++i) {
    int rbase = m0 + mq + i * 16 + ((lane >> 4) << 2);
#pragma unroll
    for (int j = 0; j < 4; ++j) {
      int col = n0 + nq + j * 16 + (lane & 15);
      float bv = bias[col];
#pragma unroll
      for (int r = 0; r < 4; ++r)
        Aout[(size_t)(rbase + r) * DD + col] = acc[i][j][r] + bv;
    }
  }
}

// ---------------- phase 2: recurrence (R11: sub-flags, 3-buffer, swizzled b32 reduce) ----------------
__global__ __launch_bounds__(512, 1) void k_recur(
    const float* __restrict__ Wh, const float* __restrict__ h0,
    const float* __restrict__ z, const float* __restrict__ sp,
    float* __restrict__ outs, float* __restrict__ hall,
    short* __restrict__ hbuf, int* __restrict__ flags) {
  __shared__ f32x4 REDS[2][2048];  // 2 x 32 KB
  const int tid = threadIdx.x;
  const int lane = tid & 63;
  const int wv = tid >> 6;         // 0..7
  const int wgid = blockIdx.x;     // 0..95
  const int fg = wgid >> 2;        // 0..23
  const int mq = wgid & 3;
  const int n0 = fg * 64;
  const int m0 = mq * 16;

  const int nl = lane & 15;
  const int hi8 = (lane >> 4) << 3;
  const int kw = wv * 192;         // wave's K-slice base

  // ---- one-time: Wh tile -> registers (f32 -> bf16) ----
  short8 bfr[6][4];
#pragma unroll
  for (int j = 0; j < 6; ++j)
#pragma unroll
    for (int f = 0; f < 4; ++f) {
      const float* gp = Wh + (size_t)(n0 + f * 16 + nl) * DD + kw + j * 32 + hi8;
      float4 a0 = *(const float4*)gp;
      float4 a1 = *(const float4*)(gp + 4);
      short8 v;
      v[0]=f2bf(a0.x); v[1]=f2bf(a0.y); v[2]=f2bf(a0.z); v[3]=f2bf(a0.w);
      v[4]=f2bf(a1.x); v[5]=f2bf(a1.y); v[6]=f2bf(a1.z); v[7]=f2bf(a1.w);
      bfr[j][f] = v;
    }

  // epilogue geometry: r = wv + 8*half keeps ri wave-uniform; c,c+1 per thread
  const int r = wv + ((lane >> 5) << 3);   // 0..15
  const int c = (lane & 31) * 2;           // 0..62 even
  const int f0 = c >> 4;
  const int c15 = c & 15;
  const int l2a = ((r >> 2) << 4) | c15;
  const int l2b = l2a + 1;
  const int ri = r & 3;
  const size_t eidx = (size_t)(m0 + r) * DD + n0 + c;       // element in [B,D]
  const size_t aoff = (size_t)(m0 + nl) * DD + kw + hi8;    // A-load base, shorts

  int* myflag = flags + ((mq * 24 + fg) * 8 + wv) * 16;     // own 64B line
  const int* cflag = flags + (((mq * 24 + wv * 3 + (lane >> 3)) * 8) + (lane & 7)) * 16;

  // 3 rotating h buffers
  short* pg = hbuf;                // read  h[t]
  short* pn = hbuf + BD;           // write h[t+1]
  short* pq = hbuf + 2 * BD;       // spare

  // init: hall[0] = h0 (f32); buf0 = bf16(h0) coherent packed; per-wave flag gen 1
  {
    float vx = h0[eidx], vy = h0[eidx + 1];
    hall[eidx] = vx; hall[eidx + 1] = vy;
    unsigned pk = (unsigned)(unsigned short)f2bf(vx)
                | ((unsigned)(unsigned short)f2bf(vy) << 16);
    st_coh_b32((int*)(pg + eidx), (int)pk);
  }
  const float sv = sp[0];
  asm volatile("s_waitcnt vmcnt(0)" ::: "memory");
  if (lane == 0) st_coh_b32(myflag, 1);

  // prefetch A, z for t = 0 (plain cached; drains during first spin)
  float pa = outs[eidx], pay = outs[eidx + 1];
  float pz = z[eidx], pzy = z[eidx + 1];

  for (int t = 0; t < TT; ++t) {
    const bool last = (t == TT - 1);

    // wait the 24 producer sub-flags (3 WGs x 8 waves); monotonic, bounded
    if (lane < 24) {
      int it = 0;
      for (;;) {
        int v = __hip_atomic_load(cflag, __ATOMIC_RELAXED, __HIP_MEMORY_SCOPE_AGENT);
        if (v >= t + 1 || ++it > (1 << 20)) break;
        __builtin_amdgcn_s_sleep(1);
      }
    }

    // 6 coherent 16B A-loads (wave's 192-k slice of rows m0..m0+15)
    const short* hp = pg + aoff;
    short8 a0, a1, a2, a3, a4, a5;
    LDQ(a0, hp, 0);
    LDQ(a1, hp, 64);
    LDQ(a2, hp, 128);
    LDQ(a3, hp, 192);
    LDQ(a4, hp, 256);
    LDQ(a5, hp, 320);
    asm volatile("s_waitcnt vmcnt(0)" ::: "memory");
    __builtin_amdgcn_sched_barrier(0);

    f32x4 acc0 = (f32x4){0,0,0,0}, acc1 = (f32x4){0,0,0,0};
    f32x4 acc2 = (f32x4){0,0,0,0}, acc3 = (f32x4){0,0,0,0};
#define MF4(aa, j) \
    acc0 = __builtin_amdgcn_mfma_f32_16x16x32_bf16(aa, bfr[j][0], acc0, 0, 0, 0); \
    acc1 = __builtin_amdgcn_mfma_f32_16x16x32_bf16(aa, bfr[j][1], acc1, 0, 0, 0); \
    acc2 = __builtin_amdgcn_mfma_f32_16x16x32_bf16(aa, bfr[j][2], acc2, 0, 0, 0); \
    acc3 = __builtin_amdgcn_mfma_f32_16x16x32_bf16(aa, bfr[j][3], acc3, 0, 0, 0);
    MF4(a0, 0) MF4(a1, 1) MF4(a2, 2) MF4(a3, 3) MF4(a4, 4) MF4(a5, 5)
#undef MF4

    // cross-wave K reduce: swizzled writes (component-rotated, bit5-XOR lane)
    f32x4* R = REDS[t & 1];
    {
      const int lsw = lane ^ ((lane >> 5) & 1);
#define WR(f, accv) { f32x4 wv_; \
      wv_[(0 + f) & 3] = accv[0]; wv_[(1 + f) & 3] = accv[1]; \
      wv_[(2 + f) & 3] = accv[2]; wv_[(3 + f) & 3] = accv[3]; \
      R[wv * 256 + f * 64 + lsw] = wv_; }
      WR(0, acc0) WR(1, acc1) WR(2, acc2) WR(3, acc3)
#undef WR
    }
    __syncthreads();
    const float* Rf = (const float*)R;
    const int ia = (f0 * 64 + (l2a ^ ((l2a >> 5) & 1))) * 4 + ((ri + f0) & 3);
    const int ib = (f0 * 64 + (l2b ^ ((l2b >> 5) & 1))) * 4 + ((ri + f0) & 3);
    float s0 = 0.f, s1 = 0.f;
#pragma unroll
    for (int w2 = 0; w2 < 8; ++w2) {
      s0 += Rf[w2 * 1024 + ia];
      s1 += Rf[w2 * 1024 + ib];
    }

    // critical path: h_new -> coherent packed store -> per-wave ack -> sub-flag
    float h0v = tanhf(pa + sv * s0);
    float h1v = tanhf(pay + sv * s1);
    if (!last) {
      unsigned pk = (unsigned)(unsigned short)f2bf(h0v)
                  | ((unsigned)(unsigned short)f2bf(h1v) << 16);
      st_coh_b32((int*)(pn + eidx), (int)pk);
      asm volatile("s_waitcnt vmcnt(0)" ::: "memory");   // this wave's h-store acked at IF
      if (lane == 0) st_coh_b32(myflag, t + 2);          // single-writer release
    }

    // off-critical-path tail (drains during the next spin)
    size_t tb = (size_t)t * BD;
    hall[tb + BD + eidx] = h0v;
    hall[tb + BD + eidx + 1] = h1v;
    outs[tb + eidx]     = h0v * (pz  / (1.f + __expf(-pz)));
    outs[tb + eidx + 1] = h1v * (pzy / (1.f + __expf(-pzy)));
    if (!last) {
      size_t nb = tb + BD + eidx;
      pa = outs[nb]; pay = outs[nb + 1];
      pz = z[nb];    pzy = z[nb + 1];
    }
    // rotate buffers: h[t+1] becomes the read buffer
    short* tmp = pg; pg = pn; pn = pq; pq = tmp;
  }
}

// ---------------- launcher ----------------
extern "C" void kernel_launch(void* const* d_in, const int* in_sizes, int n_in,
                              void* d_out, int out_size, void* d_ws, size_t ws_size,
                              hipStream_t stream) {
  const float* x  = (const float*)d_in[0];
  const float* z  = (const float*)d_in[1];
  const float* h0 = (const float*)d_in[2];
  const float* Wx = (const float*)d_in[3];
  const float* Wh = (const float*)d_in[4];
  const float* b  = (const float*)d_in[5];
  const float* lr = (const float*)d_in[6];
  const float* u  = (const float*)d_in[7];

  float* outs = (float*)d_out;
  float* hall = outs + (size_t)TBD;

  char* ws = (char*)d_ws;
  float* base  = (float*)ws;              // vA..vF (6x1536) + sS @ 36864
  float* sS    = base + 9216;
  int*   flags = (int*)(ws + 40960);      // recur: 96 WGs x 8 waves x 64B = 48 KB
  int*   pflg  = (int*)(ws + 90112);      // power: 384 x 64B = 24 KB
  short* hbuf  = (short*)(ws + 131072);   // 3 x BD bf16 = 576 KB
  short* xb    = (short*)(ws + ((size_t)1 << 20));   // bf16 x (96 MB), gated
  short* Wxb   = xb + (size_t)TBD;

  const size_t need = ((size_t)1 << 20) + ((size_t)TBD + (size_t)DD * DD) * 2 + 1024;
  const bool big = ws_size >= need;

  // one memset: vectors + sS + both flag arrays
  hipMemsetAsync(ws, 0, 114688, stream);

  // phase 1: big GEMM (longest prologue piece; enqueue first)
  if (big) {
    hipLaunchKernelGGL(k_conv, dim3(2048), dim3(256), 0, stream, x,  xb,  TBD / 8);
    hipLaunchKernelGGL(k_conv, dim3(512),  dim3(256), 0, stream, Wx, Wxb, DD * DD / 8);
    hipLaunchKernelGGL(k_gemm_b, dim3(12, 256), dim3(256), 0, stream, xb, Wxb, b, outs);
  } else {
    hipLaunchKernelGGL(k_gemm_xA, dim3(12, 256), dim3(256), 0, stream, x, Wx, b, outs);
  }

  // phase 0: fused power iteration (cooperative; internal flag barriers)
  {
    void* pargs[5] = {(void*)&Wh, (void*)&u, (void*)&lr, (void*)&base, (void*)&pflg};
    hipLaunchCooperativeKernel((const void*)k_power, dim3(384), dim3(256), pargs, 0, stream);
  }

  // phase 2: cooperative recurrence (R11)
  void* args[8] = {(void*)&Wh, (void*)&h0, (void*)&z, (void*)&sS,
                   (void*)&outs, (void*)&hall, (void*)&hbuf, (void*)&flags};
  hipLaunchCooperativeKernel((const void*)k_recur, dim3(NWG), dim3(512), args, 0, stream);
}

// Round 14
// 2195.678 us; speedup vs baseline: 1.5677x; 1.0417x over previous
//
#include <hip/hip_runtime.h>

#define DD 1536
#define TT 512
#define BB 64
#define BD (BB*DD)      /* 98304 */
#define TBD (TT*BD)     /* 50331648 */
#define NRECUR 96
#define NGEMM 160
#define NTILE 1536      /* 256 by-blocks x 6 n-tiles */

typedef __attribute__((ext_vector_type(8))) short short8;
typedef __attribute__((ext_vector_type(4))) float f32x4;

__device__ __forceinline__ short f2bf(float f) {
  unsigned u = __builtin_bit_cast(unsigned, f);
  u += 0x7FFFu + ((u >> 16) & 1u);   // RNE
  return (short)(u >> 16);
}

// coherent (device-scope, L1/L2-bypassing) 4B store -> Infinity Cache
__device__ __forceinline__ void st_coh_b32(int* p, int v) {
  asm volatile("global_store_dword %0, %1, off sc0 sc1" :: "v"(p), "v"(v) : "memory");
}

// coherent 16B load (bypasses L1/L2)
#define LDQ(dst, addr, imm) \
  asm volatile("global_load_dwordx4 %0, %1, off offset:" #imm " sc0 sc1" \
               : "=v"(dst) : "v"(addr) : "memory")

// compiler-tracked coherent 4B load
__device__ __forceinline__ float ld_coh_f(const float* p) {
  return __hip_atomic_load(p, __ATOMIC_RELAXED, __HIP_MEMORY_SCOPE_AGENT);
}

// ================= GEMM side (WGs 96..255): persistent A = x@Wx^T + b =================
__device__ __forceinline__ void gemm_side(
    char* smem, int gid, const float* __restrict__ x, const float* __restrict__ Wx,
    const float* __restrict__ bias, float* __restrict__ outs, int* __restrict__ acnt) {
  short* As = (short*)smem;             // 128 x 64 bf16 (16 KB)
  short* Bs = (short*)(smem + 16384);   // 256 x 64 bf16 (32 KB)
  const int tid = threadIdx.x;
  const int lane = tid & 63;
  const int wv = tid >> 6;
  const int mh = (wv >> 2) * 64;        // m-half (2)
  const int nq = (wv & 3) * 64;         // n-quarter (4)
  const int rr = tid >> 2;              // staging row 0..127
  const int qq = (tid & 3) * 16;        // staging col base

  for (int tile = gid; tile < NTILE; tile += NGEMM) {
    const int by = tile / 6;
    const int bx = tile - by * 6;
    const int tm0 = by * 128;
    const int tn0 = bx * 256;

    f32x4 acc[4][4];
#pragma unroll
    for (int i = 0; i < 4; ++i)
#pragma unroll
      for (int j = 0; j < 4; ++j) acc[i][j] = (f32x4){0.f, 0.f, 0.f, 0.f};

    for (int k0 = 0; k0 < DD; k0 += 64) {
      __syncthreads();
      // stage As (x rows) and Bs (Wx rows, 2 halves), f32 -> bf16
#pragma unroll
      for (int rd = 0; rd < 3; ++rd) {
        const float* src = (rd == 0) ? (x + (size_t)(tm0 + rr) * DD + k0 + qq)
                                     : (Wx + (size_t)(tn0 + (rd - 1) * 128 + rr) * DD + k0 + qq);
        float4 a0 = ((const float4*)src)[0], a1 = ((const float4*)src)[1];
        float4 a2 = ((const float4*)src)[2], a3 = ((const float4*)src)[3];
        short8 v0, v1;
        v0[0]=f2bf(a0.x); v0[1]=f2bf(a0.y); v0[2]=f2bf(a0.z); v0[3]=f2bf(a0.w);
        v0[4]=f2bf(a1.x); v0[5]=f2bf(a1.y); v0[6]=f2bf(a1.z); v0[7]=f2bf(a1.w);
        v1[0]=f2bf(a2.x); v1[1]=f2bf(a2.y); v1[2]=f2bf(a2.z); v1[3]=f2bf(a2.w);
        v1[4]=f2bf(a3.x); v1[5]=f2bf(a3.y); v1[6]=f2bf(a3.z); v1[7]=f2bf(a3.w);
        const int row = (rd == 2) ? rr + 128 : rr;
        short* dst = (rd == 0) ? As : Bs;
        const int sw = (row & 7) << 3;
        dst[0] += 0;  // no-op to keep compiler honest about aliasing? (removed below)
        *(short8*)&dst[((row & 255) * 64 + qq) ^ sw] = v0;
        *(short8*)&dst[((row & 255) * 64 + qq + 8) ^ sw] = v1;
      }
      __syncthreads();
#pragma unroll
      for (int kk = 0; kk < 64; kk += 32) {
        short8 af[4], bfr[4];
#pragma unroll
        for (int f = 0; f < 4; ++f) {
          int ar = mh + f * 16 + (lane & 15);
          int k = kk + ((lane >> 4) << 3);
          af[f] = *(const short8*)&As[(ar * 64 + k) ^ ((ar & 7) << 3)];
          int br = nq + f * 16 + (lane & 15);
          bfr[f] = *(const short8*)&Bs[(br * 64 + k) ^ ((br & 7) << 3)];
        }
#pragma unroll
        for (int i = 0; i < 4; ++i)
#pragma unroll
          for (int j = 0; j < 4; ++j)
            acc[i][j] = __builtin_amdgcn_mfma_f32_16x16x32_bf16(af[i], bfr[j], acc[i][j], 0, 0, 0);
      }
    }
    // epilogue: coherent A-stores (visible at IF to all XCDs)
#pragma unroll
    for (int i = 0; i < 4; ++i) {
      int rbase = tm0 + mh + i * 16 + ((lane >> 4) << 2);
#pragma unroll
      for (int j = 0; j < 4; ++j) {
        int col = tn0 + nq + j * 16 + (lane & 15);
        float bv = bias[col];
#pragma unroll
        for (int r = 0; r < 4; ++r)
          st_coh_b32((int*)&outs[(size_t)(rbase + r) * DD + col],
                     __builtin_bit_cast(int, acc[i][j][r] + bv));
      }
    }
    asm volatile("s_waitcnt vmcnt(0)" ::: "memory");   // A-block acked at IF
    __syncthreads();
    if (tid == 0)
      __hip_atomic_fetch_add(&acnt[by], 1, __ATOMIC_RELAXED, __HIP_MEMORY_SCOPE_AGENT);
  }
}

// ================= recur side (WGs 0..95): power -> recurrence =================
__device__ __forceinline__ void recur_side(
    char* smem, int wg,
    const float* __restrict__ Wh, const float* __restrict__ h0,
    const float* __restrict__ z, const float* __restrict__ u,
    const float* __restrict__ lr,
    float* __restrict__ outs, float* __restrict__ hall,
    short* __restrict__ hbuf, int* __restrict__ flags, int* __restrict__ pflags,
    int* __restrict__ acnt, float* __restrict__ base) {
  const int tid = threadIdx.x;
  const int lane = tid & 63;
  const int wv = tid >> 6;         // 0..7
  const int fg = wg >> 2;          // 0..23
  const int mq = wg & 3;
  const int n0 = fg * 64;
  const int m0 = mq * 16;

  float* vA = base;        float* vB = base + 1536;
  float* vC = base + 3072; float* vD = base + 4608;
  float* vE = base + 6144; float* vF = base + 7680;
  float* sS = base + 9216;

  // ---- power iteration on the 96 recur WGs (flag barriers) ----
  auto pbar = [&](int gen) {
    asm volatile("s_waitcnt vmcnt(0)" ::: "memory");
    __syncthreads();
    if (tid == 0) st_coh_b32(pflags + wg * 16, gen);
    if (tid < 96) {
      int it = 0;
      while (__hip_atomic_load(pflags + tid * 16, __ATOMIC_RELAXED, __HIP_MEMORY_SCOPE_AGENT) < gen
             && ++it < (1 << 18))
        __builtin_amdgcn_s_sleep(1);
    }
    __syncthreads();
  };
  auto colf = [&](const float* src, float* dst) {
    if (tid < 256) {
      int jt = wg % 6, ic = wg / 6;
      int j = jt * 256 + tid;
      int i0 = ic * 96;
      float a0 = 0.f, a1 = 0.f, a2 = 0.f, a3 = 0.f;
      for (int i = i0; i < i0 + 96; i += 4) {
        a0 += Wh[(size_t)(i + 0) * DD + j] * ld_coh_f(src + i + 0);
        a1 += Wh[(size_t)(i + 1) * DD + j] * ld_coh_f(src + i + 1);
        a2 += Wh[(size_t)(i + 2) * DD + j] * ld_coh_f(src + i + 2);
        a3 += Wh[(size_t)(i + 3) * DD + j] * ld_coh_f(src + i + 3);
      }
      atomicAdd(&dst[j], (a0 + a1) + (a2 + a3));
    }
  };
  auto rowf = [&](const float* src, float* dst) {
#pragma unroll
    for (int p = 0; p < 2; ++p) {
      int row = wg * 8 + wv + p * 768;
      const float* Wr = Wh + (size_t)row * DD;
      float acc = 0.f;
      for (int j = lane; j < DD; j += 64) acc += Wr[j] * ld_coh_f(src + j);
      for (int off = 32; off; off >>= 1) acc += __shfl_down(acc, off, 64);
      if (lane == 0) st_coh_b32((int*)&dst[row], __builtin_bit_cast(int, acc));
    }
  };

  colf(u,  vA); pbar(1);
  rowf(vA, vB); pbar(2);
  colf(vB, vC); pbar(3);
  rowf(vC, vD); pbar(4);
  colf(vD, vE); pbar(5);
  rowf(vE, vF); pbar(6);
  if (wg == 0) {
    float* red = (float*)smem;
    float a5 = 0.f, a6 = 0.f;
    for (int i = tid; i < DD; i += 512) {
      float v5 = ld_coh_f(vE + i), v6 = ld_coh_f(vF + i);
      a5 += v5 * v5; a6 += v6 * v6;
    }
    for (int off = 32; off; off >>= 1) { a5 += __shfl_down(a5, off, 64); a6 += __shfl_down(a6, off, 64); }
    if (lane == 0) { red[wv] = a5; red[8 + wv] = a6; }
    __syncthreads();
    if (tid == 0) {
      float s5 = 0.f, s6 = 0.f;
      for (int i = 0; i < 8; ++i) { s5 += red[i]; s6 += red[8 + i]; }
      float sigma = sqrtf(s6 / s5);
      float target = 0.999f / (1.f + expf(-lr[0]));
      st_coh_b32((int*)sS, __builtin_bit_cast(int, target / (sigma + 1e-8f)));
    }
    __syncthreads();
  }
  pbar(7);
  const float sv = ld_coh_f(sS);

  // ---- recurrence (R11/R13 protocol) ----
  f32x4* REDS = (f32x4*)smem;      // 2 x 2048 f32x4 = 64 KB
  const int nl = lane & 15;
  const int hi8 = (lane >> 4) << 3;
  const int kw = wv * 192;

  short8 bfr[6][4];
#pragma unroll
  for (int j = 0; j < 6; ++j)
#pragma unroll
    for (int f = 0; f < 4; ++f) {
      const float* gp = Wh + (size_t)(n0 + f * 16 + nl) * DD + kw + j * 32 + hi8;
      float4 a0 = *(const float4*)gp;
      float4 a1 = *(const float4*)(gp + 4);
      short8 v;
      v[0]=f2bf(a0.x); v[1]=f2bf(a0.y); v[2]=f2bf(a0.z); v[3]=f2bf(a0.w);
      v[4]=f2bf(a1.x); v[5]=f2bf(a1.y); v[6]=f2bf(a1.z); v[7]=f2bf(a1.w);
      bfr[j][f] = v;
    }

  const int r = wv + ((lane >> 5) << 3);   // 0..15
  const int c = (lane & 31) * 2;           // 0..62 even
  const int f0 = c >> 4;
  const int c15 = c & 15;
  const int l2a = ((r >> 2) << 4) | c15;
  const int l2b = l2a + 1;
  const int ri = r & 3;
  const size_t eidx = (size_t)(m0 + r) * DD + n0 + c;
  const size_t aoff = (size_t)(m0 + nl) * DD + kw + hi8;
  const int lsw = lane ^ ((lane >> 5) & 1);
  const int ia = (f0 * 64 + (l2a ^ ((l2a >> 5) & 1))) * 4 + ((ri + f0) & 3);
  const int ib = (f0 * 64 + (l2b ^ ((l2b >> 5) & 1))) * 4 + ((ri + f0) & 3);

  int* myflag = flags + ((mq * 24 + fg) * 8 + wv) * 16;
  const int* cflag = flags + (((mq * 24 + wv * 3 + (lane >> 3)) * 8) + (lane & 7)) * 16;

  short* pg = hbuf;
  short* pn = hbuf + BD;
  short* pq = hbuf + 2 * BD;

  {
    float vx = h0[eidx], vy = h0[eidx + 1];
    hall[eidx] = vx; hall[eidx + 1] = vy;
    unsigned pk = (unsigned)(unsigned short)f2bf(vx)
                | ((unsigned)(unsigned short)f2bf(vy) << 16);
    st_coh_b32((int*)(pg + eidx), (int)pk);
  }
  asm volatile("s_waitcnt vmcnt(0)" ::: "memory");
  if (lane == 0) st_coh_b32(myflag, 1);

  // bounded wave-spin until A-block `by` complete (6 n-tiles)
  auto waitA = [&](int by) {
    if (lane == 0) {
      int it = 0;
      while (__hip_atomic_load(&acnt[by], __ATOMIC_RELAXED, __HIP_MEMORY_SCOPE_AGENT) < 6
             && ++it < (1 << 18))
        __builtin_amdgcn_s_sleep(1);
    }
    __builtin_amdgcn_sched_barrier(0);
  };

  waitA(0);
  float pa = ld_coh_f(outs + eidx), pay = ld_coh_f(outs + eidx + 1);
  float pz = z[eidx], pzy = z[eidx + 1];

  for (int t = 0; t < TT; ++t) {
    const bool last = (t == TT - 1);

    if (lane < 24) {
      int it = 0;
      for (;;) {
        int v = __hip_atomic_load(cflag, __ATOMIC_RELAXED, __HIP_MEMORY_SCOPE_AGENT);
        if (v >= t + 1 || ++it > (1 << 18)) break;
        __builtin_amdgcn_s_sleep(1);
      }
    }

    const short* hp = pg + aoff;
    short8 a0, a1, a2, a3, a4, a5;
    LDQ(a0, hp, 0);
    LDQ(a1, hp, 64);
    LDQ(a2, hp, 128);
    LDQ(a3, hp, 192);
    LDQ(a4, hp, 256);
    LDQ(a5, hp, 320);
    asm volatile("s_waitcnt vmcnt(0)" ::: "memory");
    __builtin_amdgcn_sched_barrier(0);

    f32x4 acc0 = (f32x4){0,0,0,0}, acc1 = (f32x4){0,0,0,0};
    f32x4 acc2 = (f32x4){0,0,0,0}, acc3 = (f32x4){0,0,0,0};
#define MF4(aa, j) \
    acc0 = __builtin_amdgcn_mfma_f32_16x16x32_bf16(aa, bfr[j][0], acc0, 0, 0, 0); \
    acc1 = __builtin_amdgcn_mfma_f32_16x16x32_bf16(aa, bfr[j][1], acc1, 0, 0, 0); \
    acc2 = __builtin_amdgcn_mfma_f32_16x16x32_bf16(aa, bfr[j][2], acc2, 0, 0, 0); \
    acc3 = __builtin_amdgcn_mfma_f32_16x16x32_bf16(aa, bfr[j][3], acc3, 0, 0, 0);
    MF4(a0, 0) MF4(a1, 1) MF4(a2, 2) MF4(a3, 3) MF4(a4, 4) MF4(a5, 5)
#undef MF4

    f32x4* R = REDS + (size_t)(t & 1) * 2048;
#define WR(f, accv) { f32x4 wv_; \
    wv_[(0 + f) & 3] = accv[0]; wv_[(1 + f) & 3] = accv[1]; \
    wv_[(2 + f) & 3] = accv[2]; wv_[(3 + f) & 3] = accv[3]; \
    R[wv * 256 + f * 64 + lsw] = wv_; }
    WR(0, acc0) WR(1, acc1) WR(2, acc2) WR(3, acc3)
#undef WR
    __syncthreads();
    const float* Rf = (const float*)R;
    float s0 = 0.f, s1 = 0.f;
#pragma unroll
    for (int w2 = 0; w2 < 8; ++w2) {
      s0 += Rf[w2 * 1024 + ia];
      s1 += Rf[w2 * 1024 + ib];
    }

    float h0v = tanhf(pa + sv * s0);
    float h1v = tanhf(pay + sv * s1);
    if (!last) {
      unsigned pk = (unsigned)(unsigned short)f2bf(h0v)
                  | ((unsigned)(unsigned short)f2bf(h1v) << 16);
      st_coh_b32((int*)(pn + eidx), (int)pk);
      asm volatile("s_waitcnt vmcnt(0)" ::: "memory");
      if (lane == 0) st_coh_b32(myflag, t + 2);
    }

    size_t tb = (size_t)t * BD;
    hall[tb + BD + eidx] = h0v;
    hall[tb + BD + eidx + 1] = h1v;
    outs[tb + eidx]     = h0v * (pz  / (1.f + __expf(-pz)));
    outs[tb + eidx + 1] = h1v * (pzy / (1.f + __expf(-pzy)));
    if (!last) {
      waitA((t + 1) >> 1);
      size_t nb = tb + BD + eidx;
      pa = ld_coh_f(outs + nb); pay = ld_coh_f(outs + nb + 1);
      pz = z[nb]; pzy = z[nb + 1];
    }
    short* tmp = pg; pg = pn; pn = pq; pq = tmp;
  }
}

// ================= fused kernel =================
__global__ __launch_bounds__(512, 2) void k_fused(
    const float* __restrict__ Wh, const float* __restrict__ Wx,
    const float* __restrict__ h0, const float* __restrict__ x,
    const float* __restrict__ z, const float* __restrict__ u,
    const float* __restrict__ lr, const float* __restrict__ bias,
    float* __restrict__ outs, float* __restrict__ hall,
    short* __restrict__ hbuf, int* __restrict__ flags,
    int* __restrict__ pflags, int* __restrict__ acnt, float* __restrict__ base) {
  __shared__ char smem[65536];
  const int wg = blockIdx.x;
  if (wg < NRECUR)
    recur_side(smem, wg, Wh, h0, z, u, lr, outs, hall, hbuf, flags, pflags, acnt, base);
  else
    gemm_side(smem, wg - NRECUR, x, Wx, bias, outs, acnt);
}

// ================= launcher =================
extern "C" void kernel_launch(void* const* d_in, const int* in_sizes, int n_in,
                              void* d_out, int out_size, void* d_ws, size_t ws_size,
                              hipStream_t stream) {
  const float* x  = (const float*)d_in[0];
  const float* z  = (const float*)d_in[1];
  const float* h0 = (const float*)d_in[2];
  const float* Wx = (const float*)d_in[3];
  const float* Wh = (const float*)d_in[4];
  const float* b  = (const float*)d_in[5];
  const float* lr = (const float*)d_in[6];
  const float* u  = (const float*)d_in[7];

  float* outs = (float*)d_out;
  float* hall = outs + (size_t)TBD;

  char* ws = (char*)d_ws;
  float* base  = (float*)ws;              // vA..vF + sS (36868 B)
  int*   flags = (int*)(ws + 40960);      // 96 x 8 x 64 B = 48 KB
  int*   pflg  = (int*)(ws + 90112);      // 96 x 64 B = 6 KB
  int*   acnt  = (int*)(ws + 98304);      // 256 ints
  short* hbuf  = (short*)(ws + 131072);   // 3 x BD bf16 = 576 KB

  // zero vectors + sS + all flags/counters (graph-capture-safe)
  hipMemsetAsync(ws, 0, 131072, stream);

  void* args[15] = {(void*)&Wh, (void*)&Wx, (void*)&h0, (void*)&x, (void*)&z,
                    (void*)&u, (void*)&lr, (void*)&b,
                    (void*)&outs, (void*)&hall, (void*)&hbuf, (void*)&flags,
                    (void*)&pflg, (void*)&acnt, (void*)&base};
  hipLaunchCooperativeKernel((const void*)k_fused, dim3(NRECUR + NGEMM), dim3(512), args, 0, stream);
}